// Round 14
// baseline (666.278 us; speedup 1.0000x reference)
//
#include <hip/hip_runtime.h>
#include <math.h>
#include <float.h>

// Problem constants (fixed by setup_inputs)
#define NN 100000
#define EE 1600000
#define FF 128
#define DD 64
#define GG 512
#define NBLK 98    // ceil(NN/1024)
#define WPASS 25000  // fill_csr dst-window size (4 passes)

__device__ __forceinline__ unsigned short f2bf(float f) {
    unsigned u = __float_as_uint(f);
    u = (u + 0x7fff + ((u >> 16) & 1)) >> 16;   // round-to-nearest-even
    return (unsigned short)u;
}
__device__ __forceinline__ float bflo(unsigned u) { return __uint_as_float(u << 16); }
__device__ __forceinline__ float bfhi(unsigned u) { return __uint_as_float(u & 0xffff0000u); }

// ---------------- degree ----------------
__global__ void init_deg(int* degi) {
    int i = blockIdx.x * 256 + threadIdx.x;
    if (i < NN) degi[i] = 1;   // self loop
}

__global__ void edge_deg(const int* __restrict__ dst, int* degi) {
    int e = blockIdx.x * 256 + threadIdx.x;
    if (e < EE) atomicAdd(&degi[dst[e]], 1);
}

__global__ void make_dinv(const int* __restrict__ degi, float* __restrict__ dinv) {
    int i = blockIdx.x * 256 + threadIdx.x;
    if (i < NN) dinv[i] = rsqrtf((float)degi[i]);   // deg >= 1 always
}

// ---------------- hierarchical exclusive scan of indeg = degi-1 ----------------
__global__ void scan_partial(const int* __restrict__ degi, int* __restrict__ partial) {
    __shared__ int red[1024];
    int tid = threadIdx.x;
    int idx = blockIdx.x * 1024 + tid;
    red[tid] = (idx < NN) ? degi[idx] - 1 : 0;
    __syncthreads();
    #pragma unroll
    for (int off = 512; off; off >>= 1) {
        if (tid < off) red[tid] += red[tid + off];
        __syncthreads();
    }
    if (tid == 0) partial[blockIdx.x] = red[0];
}

__global__ void scan_offsets(int* __restrict__ partial, int* __restrict__ row_ptr) {
    __shared__ int tmp[128];
    int tid = threadIdx.x;   // 128 threads
    int v = (tid < NBLK) ? partial[tid] : 0;
    tmp[tid] = v;
    __syncthreads();
    #pragma unroll
    for (int off = 1; off < 128; off <<= 1) {
        int t = (tid >= off) ? tmp[tid - off] : 0;
        __syncthreads();
        tmp[tid] += t;
        __syncthreads();
    }
    if (tid < NBLK) partial[tid] = tmp[tid] - v;     // exclusive block offsets
    if (tid == NBLK - 1) row_ptr[NN] = tmp[tid];     // total == EE
}

__global__ void scan_final(const int* __restrict__ degi, const int* __restrict__ partial,
                           int* __restrict__ row_ptr, int* __restrict__ cursor) {
    __shared__ int tmp[1024];
    int tid = threadIdx.x;
    int idx = blockIdx.x * 1024 + tid;
    int v = (idx < NN) ? degi[idx] - 1 : 0;
    tmp[tid] = v;
    __syncthreads();
    #pragma unroll
    for (int off = 1; off < 1024; off <<= 1) {
        int t = (tid >= off) ? tmp[tid - off] : 0;
        __syncthreads();
        tmp[tid] += t;
        __syncthreads();
    }
    int excl = partial[blockIdx.x] + tmp[tid] - v;
    if (idx < NN) { row_ptr[idx] = excl; cursor[idx] = excl; }
}

// ---------------- CSR fill, dst-windowed (4 passes over the edge list) ----------------
// Pass p handles dst in [lo,lo+WPASS): CSR positions land in a contiguous ~3.2 MB
// window -> cache lines accumulate ~8 edges before writeback (kills 8x write amp).
__global__ void fill_csr_win(const int* __restrict__ src, const int* __restrict__ dst,
                             const float* __restrict__ dinv,
                             int* __restrict__ cursor, int2* __restrict__ cw, int lo) {
    int e = blockIdx.x * 256 + threadIdx.x;
    if (e < EE) {
        int v = dst[e];
        if ((unsigned)(v - lo) < WPASS) {
            int u = src[e];
            int pos = atomicAdd(&cursor[v], 1);
            float w = dinv[u] * dinv[v];
            cw[pos] = make_int2(u, __float_as_int(w));
        }
    }
}

// ---------------- dense transform: T = X @ W, bf16 out ----------------
// 64x64 output tile / block, 256 threads, 4x4 register tile per thread.
// K staged in 64-wide slabs (33 KB LDS -> 4 blocks/CU).
template <int K>
__global__ __launch_bounds__(256) void gemm_k(const float* __restrict__ X,
                                              const float* __restrict__ W,
                                              unsigned short* __restrict__ T2) {
    __shared__ float sX[64 * 65];   // [r][k], stride 65 (bank spread + b32 reads)
    __shared__ float sW[64 * 64];   // [k][c], contiguous (b128 reads)
    int tid = threadIdx.x;
    int row0 = blockIdx.x * 64;
    int rows = NN - row0; if (rows > 64) rows = 64;
    int r0 = (tid >> 4) << 2;       // 0,4,..,60
    int c0 = (tid & 15) << 2;       // 0,4,..,60
    float acc[4][4] = {};
    for (int k0 = 0; k0 < K; k0 += 64) {
        // stage W slab (linear, coalesced float4)
        {
            const float4* Wg = (const float4*)(W + (size_t)k0 * 64);
            float4* sW4 = (float4*)sW;
            #pragma unroll
            for (int j = 0; j < 4; ++j) sW4[tid + j * 256] = Wg[tid + j * 256];
        }
        // stage X slab: 64 rows x 64 k (float4 global reads, b32 LDS writes)
        #pragma unroll
        for (int j = 0; j < 4; ++j) {
            int flat = tid + j * 256;          // 0..1023
            int r = flat >> 4, kc = (flat & 15) << 2;
            float4 v = make_float4(0.f, 0.f, 0.f, 0.f);
            if (r < rows) v = *(const float4*)(X + (size_t)(row0 + r) * K + k0 + kc);
            sX[r * 65 + kc]     = v.x;
            sX[r * 65 + kc + 1] = v.y;
            sX[r * 65 + kc + 2] = v.z;
            sX[r * 65 + kc + 3] = v.w;
        }
        __syncthreads();
        #pragma unroll 8
        for (int k = 0; k < 64; ++k) {
            float4 b = *(const float4*)(sW + k * 64 + c0);
            float a0 = sX[r0 * 65 + k];
            float a1 = sX[(r0 + 1) * 65 + k];
            float a2 = sX[(r0 + 2) * 65 + k];
            float a3 = sX[(r0 + 3) * 65 + k];
            acc[0][0] = fmaf(a0, b.x, acc[0][0]); acc[0][1] = fmaf(a0, b.y, acc[0][1]);
            acc[0][2] = fmaf(a0, b.z, acc[0][2]); acc[0][3] = fmaf(a0, b.w, acc[0][3]);
            acc[1][0] = fmaf(a1, b.x, acc[1][0]); acc[1][1] = fmaf(a1, b.y, acc[1][1]);
            acc[1][2] = fmaf(a1, b.z, acc[1][2]); acc[1][3] = fmaf(a1, b.w, acc[1][3]);
            acc[2][0] = fmaf(a2, b.x, acc[2][0]); acc[2][1] = fmaf(a2, b.y, acc[2][1]);
            acc[2][2] = fmaf(a2, b.z, acc[2][2]); acc[2][3] = fmaf(a2, b.w, acc[2][3]);
            acc[3][0] = fmaf(a3, b.x, acc[3][0]); acc[3][1] = fmaf(a3, b.y, acc[3][1]);
            acc[3][2] = fmaf(a3, b.z, acc[3][2]); acc[3][3] = fmaf(a3, b.w, acc[3][3]);
        }
        __syncthreads();
    }
    #pragma unroll
    for (int i = 0; i < 4; ++i) {
        int r = row0 + r0 + i;
        if (r < NN) {
            ushort4 o;
            o.x = f2bf(acc[i][0]); o.y = f2bf(acc[i][1]);
            o.z = f2bf(acc[i][2]); o.w = f2bf(acc[i][3]);
            *(ushort4*)(T2 + (size_t)r * 64 + c0) = o;
        }
    }
}

// ---------------- aggregation (bf16 gather, 4 chains in flight per lane) ----------------
// One wave per node. 8 groups of 8 lanes; group g handles edges beg+grp, beg+grp+8, ...
// Unrolled x4: four independent cw->T4 gather chains per lane for memory-level parallelism.
__global__ __launch_bounds__(256) void agg_k(const uint4* __restrict__ T4,   // [N*8] uint4
                                             const float* __restrict__ dinv,
                                             const int* __restrict__ row_ptr,
                                             const int2* __restrict__ cw,
                                             const float* __restrict__ bias,
                                             float4* __restrict__ A4) {
    int node = blockIdx.x * 4 + (threadIdx.x >> 6);
    int lane = threadIdx.x & 63;
    int grp  = lane >> 3;      // 0..7 : edge slot
    int fl   = lane & 7;       // which 8-feature chunk
    int beg = row_ptr[node], end = row_ptr[node + 1];
    float a0=0,a1=0,a2=0,a3=0,a4=0,a5=0,a6=0,a7=0;
    int j = beg + grp;
    for (; j + 24 < end; j += 32) {   // four edges per iteration
        int2 c1 = cw[j];
        int2 c2 = cw[j + 8];
        int2 c3 = cw[j + 16];
        int2 c4 = cw[j + 24];
        uint4 t1 = T4[(size_t)c1.x * 8 + fl];
        uint4 t2 = T4[(size_t)c2.x * 8 + fl];
        uint4 t3 = T4[(size_t)c3.x * 8 + fl];
        uint4 t4 = T4[(size_t)c4.x * 8 + fl];
        float w1 = __int_as_float(c1.y);
        float w2 = __int_as_float(c2.y);
        float w3 = __int_as_float(c3.y);
        float w4 = __int_as_float(c4.y);
        a0 = fmaf(bflo(t1.x), w1, a0); a1 = fmaf(bfhi(t1.x), w1, a1);
        a2 = fmaf(bflo(t1.y), w1, a2); a3 = fmaf(bfhi(t1.y), w1, a3);
        a4 = fmaf(bflo(t1.z), w1, a4); a5 = fmaf(bfhi(t1.z), w1, a5);
        a6 = fmaf(bflo(t1.w), w1, a6); a7 = fmaf(bfhi(t1.w), w1, a7);
        a0 = fmaf(bflo(t2.x), w2, a0); a1 = fmaf(bfhi(t2.x), w2, a1);
        a2 = fmaf(bflo(t2.y), w2, a2); a3 = fmaf(bfhi(t2.y), w2, a3);
        a4 = fmaf(bflo(t2.z), w2, a4); a5 = fmaf(bfhi(t2.z), w2, a5);
        a6 = fmaf(bflo(t2.w), w2, a6); a7 = fmaf(bfhi(t2.w), w2, a7);
        a0 = fmaf(bflo(t3.x), w3, a0); a1 = fmaf(bfhi(t3.x), w3, a1);
        a2 = fmaf(bflo(t3.y), w3, a2); a3 = fmaf(bfhi(t3.y), w3, a3);
        a4 = fmaf(bflo(t3.z), w3, a4); a5 = fmaf(bfhi(t3.z), w3, a5);
        a6 = fmaf(bflo(t3.w), w3, a6); a7 = fmaf(bfhi(t3.w), w3, a7);
        a0 = fmaf(bflo(t4.x), w4, a0); a1 = fmaf(bfhi(t4.x), w4, a1);
        a2 = fmaf(bflo(t4.y), w4, a2); a3 = fmaf(bfhi(t4.y), w4, a3);
        a4 = fmaf(bflo(t4.z), w4, a4); a5 = fmaf(bfhi(t4.z), w4, a5);
        a6 = fmaf(bflo(t4.w), w4, a6); a7 = fmaf(bfhi(t4.w), w4, a7);
    }
    for (; j < end; j += 8) {
        int2 c = cw[j];
        float w = __int_as_float(c.y);
        uint4 t = T4[(size_t)c.x * 8 + fl];
        a0 = fmaf(bflo(t.x), w, a0); a1 = fmaf(bfhi(t.x), w, a1);
        a2 = fmaf(bflo(t.y), w, a2); a3 = fmaf(bfhi(t.y), w, a3);
        a4 = fmaf(bflo(t.z), w, a4); a5 = fmaf(bfhi(t.z), w, a5);
        a6 = fmaf(bflo(t.w), w, a6); a7 = fmaf(bfhi(t.w), w, a7);
    }
    // butterfly-sum the 8 groups (lanes xor 8, 16, 32)
    #pragma unroll
    for (int m = 8; m <= 32; m <<= 1) {
        a0 += __shfl_xor(a0, m); a1 += __shfl_xor(a1, m);
        a2 += __shfl_xor(a2, m); a3 += __shfl_xor(a3, m);
        a4 += __shfl_xor(a4, m); a5 += __shfl_xor(a5, m);
        a6 += __shfl_xor(a6, m); a7 += __shfl_xor(a7, m);
    }
    if (grp == 0) {   // lanes 0..7 write the 64-float row (32 B each)
        float dv = dinv[node];
        float s = dv * dv;
        uint4 t = T4[(size_t)node * 8 + fl];
        const float* b = &bias[fl * 8];
        float4 o0, o1;
        o0.x = tanhf(fmaf(bflo(t.x), s, a0) + b[0]);
        o0.y = tanhf(fmaf(bfhi(t.x), s, a1) + b[1]);
        o0.z = tanhf(fmaf(bflo(t.y), s, a2) + b[2]);
        o0.w = tanhf(fmaf(bfhi(t.y), s, a3) + b[3]);
        o1.x = tanhf(fmaf(bflo(t.z), s, a4) + b[4]);
        o1.y = tanhf(fmaf(bfhi(t.z), s, a5) + b[5]);
        o1.z = tanhf(fmaf(bflo(t.w), s, a6) + b[6]);
        o1.w = tanhf(fmaf(bfhi(t.w), s, a7) + b[7]);
        A4[(size_t)node * 16 + fl * 2]     = o0;
        A4[(size_t)node * 16 + fl * 2 + 1] = o1;
    }
}

// ---------------- pooling ----------------
// batch_index is SORTED: gstart via boundary detection (no atomics, no scan).
__global__ void find_bounds(const int* __restrict__ batch, int* __restrict__ gstart) {
    int i = blockIdx.x * 256 + threadIdx.x;
    if (i >= NN) return;
    int cur = batch[i];
    int prev = (i == 0) ? -1 : batch[i - 1];
    for (int g = prev + 1; g <= cur; ++g) gstart[g] = i;   // covers empty graphs
    if (i == NN - 1) {
        for (int g = cur + 1; g <= GG; ++g) gstart[g] = NN;
    }
}

__global__ __launch_bounds__(256) void pool_k(const float* __restrict__ H,
                                              const int* __restrict__ gstart,
                                              float* __restrict__ hidden) {
    __shared__ float smax[4][64], ssum[4][64];
    int g = blockIdx.x;
    int wave = threadIdx.x >> 6, lane = threadIdx.x & 63;
    int beg = gstart[g], end = gstart[g + 1];
    float mx = -FLT_MAX, sm = 0.f;
    for (int i = beg + wave; i < end; i += 4) {
        float v = H[(size_t)i * 64 + lane];
        mx = fmaxf(mx, v);
        sm += v;
    }
    smax[wave][lane] = mx; ssum[wave][lane] = sm;
    __syncthreads();
    if (wave == 0) {
        mx = fmaxf(fmaxf(smax[0][lane], smax[1][lane]), fmaxf(smax[2][lane], smax[3][lane]));
        sm = ssum[0][lane] + ssum[1][lane] + ssum[2][lane] + ssum[3][lane];
        int cnt = end - beg;
        hidden[g * 128 + lane]      = (cnt > 0) ? mx : 0.f;
        hidden[g * 128 + 64 + lane] = sm / fmaxf((float)cnt, 1.f);
    }
}

__global__ void head_k(const float* __restrict__ hidden, const float* __restrict__ Wout,
                       const float* __restrict__ bout, float* __restrict__ out) {
    int g = blockIdx.x, lane = threadIdx.x;   // 64 threads
    float v = hidden[g * 128 + lane] * Wout[lane]
            + hidden[g * 128 + 64 + lane] * Wout[64 + lane];
    #pragma unroll
    for (int off = 32; off; off >>= 1) v += __shfl_down(v, off);
    if (lane == 0) out[g] = 1.f / (1.f + expf(-(v + bout[0])));
}

// ---------------- launch ----------------
extern "C" void kernel_launch(void* const* d_in, const int* in_sizes, int n_in,
                              void* d_out, int out_size, void* d_ws, size_t ws_size,
                              hipStream_t stream) {
    const float* x     = (const float*)d_in[0];
    const int*   ei    = (const int*)d_in[1];
    const int*   src   = ei;
    const int*   dst   = ei + EE;
    const int*   batch = (const int*)d_in[2];
    const float* W0 = (const float*)d_in[4];  const float* b0 = (const float*)d_in[5];
    const float* W1 = (const float*)d_in[6];  const float* b1 = (const float*)d_in[7];
    const float* W2 = (const float*)d_in[8];  const float* b2 = (const float*)d_in[9];
    const float* W3 = (const float*)d_in[10]; const float* b3 = (const float*)d_in[11];
    const float* Wout = (const float*)d_in[12]; const float* bout = (const float*)d_in[13];

    float* out    = (float*)d_out;
    float* hidden = out + GG;     // [G,128] portion of d_out

    char*  w = (char*)d_ws;
    size_t off = 0;
    auto alloc = [&](size_t bytes) -> char* {
        char* p = w + off;
        off = (off + bytes + 255) & ~(size_t)255;
        return p;
    };
    int*   degi    = (int*)  alloc(NN * 4);
    float* dinv    = (float*)alloc(NN * 4);
    int*   row_ptr = (int*)  alloc((NN + 1) * 4);
    int*   cursor  = (int*)  alloc(NN * 4);
    int*   partial = (int*)  alloc(NBLK * 4);
    int2*  cw      = (int2*) alloc((size_t)EE * 8);
    unsigned short* T2 = (unsigned short*)alloc((size_t)NN * 64 * 2);   // bf16
    float* A       = (float*)alloc((size_t)NN * 64 * 4);
    int*   gstart  = (int*)  alloc((GG + 1) * 4);
    (void)ws_size; (void)in_sizes; (void)n_in; (void)out_size;

    // degree + CSR offsets (hierarchical scan)
    init_deg<<<(NN + 255) / 256, 256, 0, stream>>>(degi);
    edge_deg<<<(EE + 255) / 256, 256, 0, stream>>>(dst, degi);
    scan_partial<<<NBLK, 1024, 0, stream>>>(degi, partial);
    scan_offsets<<<1, 128, 0, stream>>>(partial, row_ptr);
    scan_final<<<NBLK, 1024, 0, stream>>>(degi, partial, row_ptr, cursor);
    make_dinv<<<(NN + 255) / 256, 256, 0, stream>>>(degi, dinv);
    // CSR fill in 4 dst-windows (contiguous write regions -> low write amplification)
    for (int lo = 0; lo < NN; lo += WPASS)
        fill_csr_win<<<(EE + 255) / 256, 256, 0, stream>>>(src, dst, dinv, cursor, cw, lo);

    // pooling prep: boundary detection on sorted batch_index
    find_bounds<<<(NN + 255) / 256, 256, 0, stream>>>(batch, gstart);

    // 4 GCN layers (transform(bf16) -> aggregate+bias+tanh)
    const int GB = (NN + 63) / 64;
    gemm_k<FF><<<GB, 256, 0, stream>>>(x, W0, T2);
    agg_k<<<NN / 4, 256, 0, stream>>>((const uint4*)T2, dinv, row_ptr, cw, b0, (float4*)A);
    gemm_k<DD><<<GB, 256, 0, stream>>>(A, W1, T2);
    agg_k<<<NN / 4, 256, 0, stream>>>((const uint4*)T2, dinv, row_ptr, cw, b1, (float4*)A);
    gemm_k<DD><<<GB, 256, 0, stream>>>(A, W2, T2);
    agg_k<<<NN / 4, 256, 0, stream>>>((const uint4*)T2, dinv, row_ptr, cw, b2, (float4*)A);
    gemm_k<DD><<<GB, 256, 0, stream>>>(A, W3, T2);
    agg_k<<<NN / 4, 256, 0, stream>>>((const uint4*)T2, dinv, row_ptr, cw, b3, (float4*)A);

    // pooling + head
    pool_k<<<GG, 256, 0, stream>>>(A, gstart, hidden);
    head_k<<<GG, 64, 0, stream>>>(hidden, Wout, bout, out);
}

// Round 17
// 649.212 us; speedup vs baseline: 1.0263x; 1.0263x over previous
//
#include <hip/hip_runtime.h>
#include <math.h>
#include <float.h>

// Problem constants (fixed by setup_inputs)
#define NN 100000
#define EE 1600000
#define FF 128
#define DD 64
#define GG 512
#define NBLK 98   // ceil(NN/1024)

typedef __attribute__((ext_vector_type(8))) short bf16x8;   // 8 bf16 (4 VGPRs)
typedef __attribute__((ext_vector_type(4))) float f32x4;

__device__ __forceinline__ unsigned short f2bf(float f) {
    unsigned u = __float_as_uint(f);
    u = (u + 0x7fff + ((u >> 16) & 1)) >> 16;   // round-to-nearest-even
    return (unsigned short)u;
}
__device__ __forceinline__ float bflo(unsigned u) { return __uint_as_float(u << 16); }
__device__ __forceinline__ float bfhi(unsigned u) { return __uint_as_float(u & 0xffff0000u); }
__device__ __forceinline__ float bfs(unsigned short u) { return __uint_as_float((unsigned)u << 16); }

// ---------------- degree ----------------
__global__ void init_deg(int* degi) {
    int i = blockIdx.x * 256 + threadIdx.x;
    if (i < NN) degi[i] = 1;   // self loop
}

__global__ void edge_deg(const int* __restrict__ dst, int* degi) {
    int e = blockIdx.x * 256 + threadIdx.x;
    if (e < EE) atomicAdd(&degi[dst[e]], 1);
}

__global__ void make_dinv(const int* __restrict__ degi, float* __restrict__ dinv) {
    int i = blockIdx.x * 256 + threadIdx.x;
    if (i < NN) dinv[i] = rsqrtf((float)degi[i]);   // deg >= 1 always
}

// ---------------- hierarchical exclusive scan of indeg = degi-1 ----------------
__global__ void scan_partial(const int* __restrict__ degi, int* __restrict__ partial) {
    __shared__ int red[1024];
    int tid = threadIdx.x;
    int idx = blockIdx.x * 1024 + tid;
    red[tid] = (idx < NN) ? degi[idx] - 1 : 0;
    __syncthreads();
    #pragma unroll
    for (int off = 512; off; off >>= 1) {
        if (tid < off) red[tid] += red[tid + off];
        __syncthreads();
    }
    if (tid == 0) partial[blockIdx.x] = red[0];
}

__global__ void scan_offsets(int* __restrict__ partial, int* __restrict__ row_ptr) {
    __shared__ int tmp[128];
    int tid = threadIdx.x;   // 128 threads
    int v = (tid < NBLK) ? partial[tid] : 0;
    tmp[tid] = v;
    __syncthreads();
    #pragma unroll
    for (int off = 1; off < 128; off <<= 1) {
        int t = (tid >= off) ? tmp[tid - off] : 0;
        __syncthreads();
        tmp[tid] += t;
        __syncthreads();
    }
    if (tid < NBLK) partial[tid] = tmp[tid] - v;     // exclusive block offsets
    if (tid == NBLK - 1) row_ptr[NN] = tmp[tid];     // total == EE
}

__global__ void scan_final(const int* __restrict__ degi, const int* __restrict__ partial,
                           int* __restrict__ row_ptr, int* __restrict__ cursor) {
    __shared__ int tmp[1024];
    int tid = threadIdx.x;
    int idx = blockIdx.x * 1024 + tid;
    int v = (idx < NN) ? degi[idx] - 1 : 0;
    tmp[tid] = v;
    __syncthreads();
    #pragma unroll
    for (int off = 1; off < 1024; off <<= 1) {
        int t = (tid >= off) ? tmp[tid - off] : 0;
        __syncthreads();
        tmp[tid] += t;
        __syncthreads();
    }
    int excl = partial[blockIdx.x] + tmp[tid] - v;
    if (idx < NN) { row_ptr[idx] = excl; cursor[idx] = excl; }
}

// ---------------- CSR fill (single pass) ----------------
__global__ void fill_csr(const int* __restrict__ src, const int* __restrict__ dst,
                         const float* __restrict__ dinv,
                         int* __restrict__ cursor, int2* __restrict__ cw) {
    int e = blockIdx.x * 256 + threadIdx.x;
    if (e < EE) {
        int u = src[e], v = dst[e];
        int pos = atomicAdd(&cursor[v], 1);
        float w = dinv[u] * dinv[v];
        cw[pos] = make_int2(u, __float_as_int(w));
    }
}

// ---------------- dense transform via MFMA: T2 = bf16(X @ W) ----------------
// 64 rows x 64 cols per block, 4 waves; wave w owns rows [16w,16w+16).
// mfma_f32_16x16x32_bf16: A row=l&15, k=(l>>4)*8+e; B col=l&15, same k.
// C/D: col=lane&15, row=(lane>>4)*4+reg  [m89-verified].
// LDS rows padded +8 bf16 -> stride 144B/272B: 16B-aligned b128, 2-way bank (free).
template <int K, typename InT>
__global__ __launch_bounds__(256) void gemm_mfma(const InT* __restrict__ X,
                                                 const float* __restrict__ W,
                                                 unsigned short* __restrict__ T2) {
    constexpr int KP = K + 8;
    __shared__ unsigned short sA[64 * KP];    // [row][k]
    __shared__ unsigned short sWt[64 * KP];   // [col][k]  (W transposed)
    int tid = threadIdx.x;
    int row0 = blockIdx.x * 64;

    // stage W^T (coalesced read, transposed LDS write)
    for (int i = tid; i < K * 64; i += 256) {
        int k = i >> 6, c = i & 63;
        sWt[c * KP + k] = f2bf(W[k * 64 + c]);
    }
    // stage X rows as bf16
    for (int i = tid; i < 64 * K; i += 256) {
        int r = i / K, k = i % K;
        int gr = row0 + r;
        unsigned short v = 0;
        if (gr < NN) {
            if constexpr (sizeof(InT) == 4) v = f2bf((float)X[(size_t)gr * K + k]);
            else                            v = (unsigned short)X[(size_t)gr * K + k];
        }
        sA[r * KP + k] = v;
    }
    __syncthreads();

    int wv = tid >> 6, l = tid & 63;
    int tr = l & 15;            // A row / B col / D col within tile
    int kq = (l >> 4) * 8;      // k group offset
    const unsigned short* pA = sA + (wv * 16 + tr) * KP + kq;
    const unsigned short* pB = sWt + tr * KP + kq;
    f32x4 a0 = {0,0,0,0}, a1 = {0,0,0,0}, a2 = {0,0,0,0}, a3 = {0,0,0,0};
    #pragma unroll
    for (int k0 = 0; k0 < K; k0 += 32) {
        bf16x8 af = *(const bf16x8*)(pA + k0);
        a0 = __builtin_amdgcn_mfma_f32_16x16x32_bf16(af, *(const bf16x8*)(pB + 0 * 16 * KP + k0), a0, 0, 0, 0);
        a1 = __builtin_amdgcn_mfma_f32_16x16x32_bf16(af, *(const bf16x8*)(pB + 1 * 16 * KP + k0), a1, 0, 0, 0);
        a2 = __builtin_amdgcn_mfma_f32_16x16x32_bf16(af, *(const bf16x8*)(pB + 2 * 16 * KP + k0), a2, 0, 0, 0);
        a3 = __builtin_amdgcn_mfma_f32_16x16x32_bf16(af, *(const bf16x8*)(pB + 3 * 16 * KP + k0), a3, 0, 0, 0);
    }
    int orow0 = row0 + wv * 16 + (l >> 4) * 4;
    #pragma unroll
    for (int reg = 0; reg < 4; ++reg) {
        int r = orow0 + reg;
        if (r < NN) {
            size_t base = (size_t)r * 64 + tr;
            T2[base]      = f2bf(a0[reg]);
            T2[base + 16] = f2bf(a1[reg]);
            T2[base + 32] = f2bf(a2[reg]);
            T2[base + 48] = f2bf(a3[reg]);
        }
    }
}

// ---------------- aggregation (bf16 gather, 4 chains in flight, bf16 output) ----------------
__global__ __launch_bounds__(256) void agg_k(const uint4* __restrict__ T4,   // [N*8] uint4
                                             const float* __restrict__ dinv,
                                             const int* __restrict__ row_ptr,
                                             const int2* __restrict__ cw,
                                             const float* __restrict__ bias,
                                             uint4* __restrict__ A4) {      // bf16 out
    int node = blockIdx.x * 4 + (threadIdx.x >> 6);
    int lane = threadIdx.x & 63;
    int grp  = lane >> 3;      // 0..7 : edge slot
    int fl   = lane & 7;       // which 8-feature chunk
    int beg = row_ptr[node], end = row_ptr[node + 1];
    float a0=0,a1=0,a2=0,a3=0,a4=0,a5=0,a6=0,a7=0;
    int j = beg + grp;
    for (; j + 24 < end; j += 32) {
        int2 c1 = cw[j];
        int2 c2 = cw[j + 8];
        int2 c3 = cw[j + 16];
        int2 c4 = cw[j + 24];
        uint4 t1 = T4[(size_t)c1.x * 8 + fl];
        uint4 t2 = T4[(size_t)c2.x * 8 + fl];
        uint4 t3 = T4[(size_t)c3.x * 8 + fl];
        uint4 t4 = T4[(size_t)c4.x * 8 + fl];
        float w1 = __int_as_float(c1.y);
        float w2 = __int_as_float(c2.y);
        float w3 = __int_as_float(c3.y);
        float w4 = __int_as_float(c4.y);
        a0 = fmaf(bflo(t1.x), w1, a0); a1 = fmaf(bfhi(t1.x), w1, a1);
        a2 = fmaf(bflo(t1.y), w1, a2); a3 = fmaf(bfhi(t1.y), w1, a3);
        a4 = fmaf(bflo(t1.z), w1, a4); a5 = fmaf(bfhi(t1.z), w1, a5);
        a6 = fmaf(bflo(t1.w), w1, a6); a7 = fmaf(bfhi(t1.w), w1, a7);
        a0 = fmaf(bflo(t2.x), w2, a0); a1 = fmaf(bfhi(t2.x), w2, a1);
        a2 = fmaf(bflo(t2.y), w2, a2); a3 = fmaf(bfhi(t2.y), w2, a3);
        a4 = fmaf(bflo(t2.z), w2, a4); a5 = fmaf(bfhi(t2.z), w2, a5);
        a6 = fmaf(bflo(t2.w), w2, a6); a7 = fmaf(bfhi(t2.w), w2, a7);
        a0 = fmaf(bflo(t3.x), w3, a0); a1 = fmaf(bfhi(t3.x), w3, a1);
        a2 = fmaf(bflo(t3.y), w3, a2); a3 = fmaf(bfhi(t3.y), w3, a3);
        a4 = fmaf(bflo(t3.z), w3, a4); a5 = fmaf(bfhi(t3.z), w3, a5);
        a6 = fmaf(bflo(t3.w), w3, a6); a7 = fmaf(bfhi(t3.w), w3, a7);
        a0 = fmaf(bflo(t4.x), w4, a0); a1 = fmaf(bfhi(t4.x), w4, a1);
        a2 = fmaf(bflo(t4.y), w4, a2); a3 = fmaf(bfhi(t4.y), w4, a3);
        a4 = fmaf(bflo(t4.z), w4, a4); a5 = fmaf(bfhi(t4.z), w4, a5);
        a6 = fmaf(bflo(t4.w), w4, a6); a7 = fmaf(bfhi(t4.w), w4, a7);
    }
    for (; j < end; j += 8) {
        int2 c = cw[j];
        float w = __int_as_float(c.y);
        uint4 t = T4[(size_t)c.x * 8 + fl];
        a0 = fmaf(bflo(t.x), w, a0); a1 = fmaf(bfhi(t.x), w, a1);
        a2 = fmaf(bflo(t.y), w, a2); a3 = fmaf(bfhi(t.y), w, a3);
        a4 = fmaf(bflo(t.z), w, a4); a5 = fmaf(bfhi(t.z), w, a5);
        a6 = fmaf(bflo(t.w), w, a6); a7 = fmaf(bfhi(t.w), w, a7);
    }
    #pragma unroll
    for (int m = 8; m <= 32; m <<= 1) {
        a0 += __shfl_xor(a0, m); a1 += __shfl_xor(a1, m);
        a2 += __shfl_xor(a2, m); a3 += __shfl_xor(a3, m);
        a4 += __shfl_xor(a4, m); a5 += __shfl_xor(a5, m);
        a6 += __shfl_xor(a6, m); a7 += __shfl_xor(a7, m);
    }
    if (grp == 0) {   // lanes 0..7 write 8 bf16 feats (16 B) each
        float dv = dinv[node];
        float s = dv * dv;
        uint4 t = T4[(size_t)node * 8 + fl];
        const float* b = &bias[fl * 8];
        float v0 = tanhf(fmaf(bflo(t.x), s, a0) + b[0]);
        float v1 = tanhf(fmaf(bfhi(t.x), s, a1) + b[1]);
        float v2 = tanhf(fmaf(bflo(t.y), s, a2) + b[2]);
        float v3 = tanhf(fmaf(bfhi(t.y), s, a3) + b[3]);
        float v4 = tanhf(fmaf(bflo(t.z), s, a4) + b[4]);
        float v5 = tanhf(fmaf(bfhi(t.z), s, a5) + b[5]);
        float v6 = tanhf(fmaf(bflo(t.w), s, a6) + b[6]);
        float v7 = tanhf(fmaf(bfhi(t.w), s, a7) + b[7]);
        uint4 o;
        o.x = (unsigned)f2bf(v0) | ((unsigned)f2bf(v1) << 16);
        o.y = (unsigned)f2bf(v2) | ((unsigned)f2bf(v3) << 16);
        o.z = (unsigned)f2bf(v4) | ((unsigned)f2bf(v5) << 16);
        o.w = (unsigned)f2bf(v6) | ((unsigned)f2bf(v7) << 16);
        A4[(size_t)node * 8 + fl] = o;
    }
}

// ---------------- pooling ----------------
// batch_index is SORTED: gstart via boundary detection (no atomics, no scan).
__global__ void find_bounds(const int* __restrict__ batch, int* __restrict__ gstart) {
    int i = blockIdx.x * 256 + threadIdx.x;
    if (i >= NN) return;
    int cur = batch[i];
    int prev = (i == 0) ? -1 : batch[i - 1];
    for (int g = prev + 1; g <= cur; ++g) gstart[g] = i;   // covers empty graphs
    if (i == NN - 1) {
        for (int g = cur + 1; g <= GG; ++g) gstart[g] = NN;
    }
}

__global__ __launch_bounds__(256) void pool_k(const unsigned short* __restrict__ H2,  // bf16
                                              const int* __restrict__ gstart,
                                              float* __restrict__ hidden) {
    __shared__ float smax[4][64], ssum[4][64];
    int g = blockIdx.x;
    int wave = threadIdx.x >> 6, lane = threadIdx.x & 63;
    int beg = gstart[g], end = gstart[g + 1];
    float mx = -FLT_MAX, sm = 0.f;
    for (int i = beg + wave; i < end; i += 4) {
        float v = bfs(H2[(size_t)i * 64 + lane]);
        mx = fmaxf(mx, v);
        sm += v;
    }
    smax[wave][lane] = mx; ssum[wave][lane] = sm;
    __syncthreads();
    if (wave == 0) {
        mx = fmaxf(fmaxf(smax[0][lane], smax[1][lane]), fmaxf(smax[2][lane], smax[3][lane]));
        sm = ssum[0][lane] + ssum[1][lane] + ssum[2][lane] + ssum[3][lane];
        int cnt = end - beg;
        hidden[g * 128 + lane]      = (cnt > 0) ? mx : 0.f;
        hidden[g * 128 + 64 + lane] = sm / fmaxf((float)cnt, 1.f);
    }
}

__global__ void head_k(const float* __restrict__ hidden, const float* __restrict__ Wout,
                       const float* __restrict__ bout, float* __restrict__ out) {
    int g = blockIdx.x, lane = threadIdx.x;   // 64 threads
    float v = hidden[g * 128 + lane] * Wout[lane]
            + hidden[g * 128 + 64 + lane] * Wout[64 + lane];
    #pragma unroll
    for (int off = 32; off; off >>= 1) v += __shfl_down(v, off);
    if (lane == 0) out[g] = 1.f / (1.f + expf(-(v + bout[0])));
}

// ---------------- launch ----------------
extern "C" void kernel_launch(void* const* d_in, const int* in_sizes, int n_in,
                              void* d_out, int out_size, void* d_ws, size_t ws_size,
                              hipStream_t stream) {
    const float* x     = (const float*)d_in[0];
    const int*   ei    = (const int*)d_in[1];
    const int*   src   = ei;
    const int*   dst   = ei + EE;
    const int*   batch = (const int*)d_in[2];
    const float* W0 = (const float*)d_in[4];  const float* b0 = (const float*)d_in[5];
    const float* W1 = (const float*)d_in[6];  const float* b1 = (const float*)d_in[7];
    const float* W2 = (const float*)d_in[8];  const float* b2 = (const float*)d_in[9];
    const float* W3 = (const float*)d_in[10]; const float* b3 = (const float*)d_in[11];
    const float* Wout = (const float*)d_in[12]; const float* bout = (const float*)d_in[13];

    float* out    = (float*)d_out;
    float* hidden = out + GG;     // [G,128] portion of d_out

    char*  w = (char*)d_ws;
    size_t off = 0;
    auto alloc = [&](size_t bytes) -> char* {
        char* p = w + off;
        off = (off + bytes + 255) & ~(size_t)255;
        return p;
    };
    int*   degi    = (int*)  alloc(NN * 4);
    float* dinv    = (float*)alloc(NN * 4);
    int*   row_ptr = (int*)  alloc((NN + 1) * 4);
    int*   cursor  = (int*)  alloc(NN * 4);
    int*   partial = (int*)  alloc(NBLK * 4);
    int2*  cw      = (int2*) alloc((size_t)EE * 8);
    unsigned short* T2 = (unsigned short*)alloc((size_t)NN * 64 * 2);   // bf16
    unsigned short* A2 = (unsigned short*)alloc((size_t)NN * 64 * 2);   // bf16
    int*   gstart  = (int*)  alloc((GG + 1) * 4);
    (void)ws_size; (void)in_sizes; (void)n_in; (void)out_size;

    // degree + CSR offsets (hierarchical scan)
    init_deg<<<(NN + 255) / 256, 256, 0, stream>>>(degi);
    edge_deg<<<(EE + 255) / 256, 256, 0, stream>>>(dst, degi);
    scan_partial<<<NBLK, 1024, 0, stream>>>(degi, partial);
    scan_offsets<<<1, 128, 0, stream>>>(partial, row_ptr);
    scan_final<<<NBLK, 1024, 0, stream>>>(degi, partial, row_ptr, cursor);
    make_dinv<<<(NN + 255) / 256, 256, 0, stream>>>(degi, dinv);
    fill_csr<<<(EE + 255) / 256, 256, 0, stream>>>(src, dst, dinv, cursor, cw);

    // pooling prep: boundary detection on sorted batch_index
    find_bounds<<<(NN + 255) / 256, 256, 0, stream>>>(batch, gstart);

    // 4 GCN layers (MFMA transform(bf16) -> aggregate+bias+tanh(bf16))
    const int GB = (NN + 63) / 64;
    gemm_mfma<FF, float><<<GB, 256, 0, stream>>>(x, W0, T2);
    agg_k<<<NN / 4, 256, 0, stream>>>((const uint4*)T2, dinv, row_ptr, cw, b0, (uint4*)A2);
    gemm_mfma<DD, unsigned short><<<GB, 256, 0, stream>>>(A2, W1, T2);
    agg_k<<<NN / 4, 256, 0, stream>>>((const uint4*)T2, dinv, row_ptr, cw, b1, (uint4*)A2);
    gemm_mfma<DD, unsigned short><<<GB, 256, 0, stream>>>(A2, W2, T2);
    agg_k<<<NN / 4, 256, 0, stream>>>((const uint4*)T2, dinv, row_ptr, cw, b2, (uint4*)A2);
    gemm_mfma<DD, unsigned short><<<GB, 256, 0, stream>>>(A2, W3, T2);
    agg_k<<<NN / 4, 256, 0, stream>>>((const uint4*)T2, dinv, row_ptr, cw, b3, (uint4*)A2);

    // pooling + head
    pool_k<<<GG, 256, 0, stream>>>(A2, gstart, hidden);
    head_k<<<GG, 64, 0, stream>>>(hidden, Wout, bout, out);
}